// Round 2
// baseline (137.428 us; speedup 1.0000x reference)
//
#include <hip/hip_runtime.h>

#define DIM 6
#define NSEG 65535
#define CH 64            // segments per chunk
#define NCHUNK 1024      // NCHUNK*CH >= NSEG

// Padded partial-signature layout (per chunk), stride in floats.
// 16B-aligned sections: L1@0(6), L2@8(36), L3@48(216), L4@264(1296)
#define PSTRIDE 1568
#define PL1 0
#define PL2 8
#define PL3 48
#define PL4 264
#define NGRP 259         // 1 + 6 + 36 + 216 output groups of 6

// ---------------- Kernel 1: one wave per chunk, register-resident Chen fold -
// (UNCHANGED from the 101 µs round-0 configuration.)
// Lane t<36 owns pair ab=t (a=ab/6, b=ab%6): S4 row (36 regs), S3 row (6),
// S2[ab] (1), private S1[a] (1).  NO dynamic indexing of register arrays:
// lane-dependent dx_a/dx_b come from lane-addressed LDS reads.
__global__ __launch_bounds__(64) void sig_fold(const float* __restrict__ x,
                                               float* __restrict__ part) {
    __shared__ float dxs[CH * 8];   // dx row j at 8-float stride
    const int t = threadIdx.x;
    const int c = blockIdx.x;
    const int j0 = c * CH;
    const int cnt = min(CH, NSEG - j0);    // 64, or 63 for the last chunk

    for (int f = t; f < CH * 8; f += 64) dxs[f] = 0.f;
    __syncthreads();
    const float* xb = x + (size_t)j0 * DIM;
    for (int f = t; f < cnt * DIM; f += 64) {
        int j = f / 6, k = f - j * 6;
        dxs[j * 8 + k] = xb[f + 6] - xb[f];
    }
    __syncthreads();

    const int ab = (t < 36) ? t : 35;
    const int a = ab / 6, b = ab - a * 6;
    const float* dxap = dxs + a;    // lane-varying LDS bases
    const float* dxbp = dxs + b;

    float r4[36], r3[6], r2 = 0.f, s1 = 0.f;
#pragma unroll
    for (int i = 0; i < 36; ++i) r4[i] = 0.f;
#pragma unroll
    for (int i = 0; i < 6; ++i) r3[i] = 0.f;

#pragma unroll 2
    for (int j = 0; j < CH; ++j) {
        const float4 q0 = *(const float4*)(dxs + j * 8);
        const float2 q1 = *(const float2*)(dxs + j * 8 + 4);
        const float dxv[6] = {q0.x, q0.y, q0.z, q0.w, q1.x, q1.y}; // const-idx only
        const float dxa = dxap[j * 8];   // ds_read lane-addressed
        const float dxb = dxbp[j * 8];

        // t2 = S2 + dx_b*(S1/3 + dx_a/12)            (old S2, S1)
        float t2 = fmaf(dxb, fmaf(dxa, (1.f / 12.f), s1 * (1.f / 3.f)), r2);
        float t2h = 0.5f * t2;                        // *0.5 is exact
        // S4[cd] += (S3[c] + t2*0.5*dx[c]) * dx[d]   (old S3)
        float w[6];
#pragma unroll
        for (int cc = 0; cc < 6; ++cc) w[cc] = fmaf(t2h, dxv[cc], r3[cc]);
#pragma unroll
        for (int cc = 0; cc < 6; ++cc)
#pragma unroll
            for (int d = 0; d < 6; ++d)
                r4[cc * 6 + d] = fmaf(w[cc], dxv[d], r4[cc * 6 + d]);
        // S3[c] += (S2 + t3*0.5*dx_b) * dx[c],  t3 = S1 + dx_a/3
        float t3 = fmaf(dxa, (1.f / 3.f), s1);
        float v = fmaf(0.5f * t3, dxb, r2);
#pragma unroll
        for (int cc = 0; cc < 6; ++cc) r3[cc] = fmaf(v, dxv[cc], r3[cc]);
        // S2 += (S1 + 0.5*dx_a) * dx_b ; S1 += dx_a
        r2 = fmaf(fmaf(0.5f, dxa, s1), dxb, r2);
        s1 += dxa;
    }

    if (t < 36) {
        float* P = part + (size_t)c * PSTRIDE;
        if (a == b) P[PL1 + a] = s1;
        P[PL2 + ab] = r2;
        float* p3 = P + PL3 + ab * 6;
        *(float2*)(p3 + 0) = make_float2(r3[0], r3[1]);
        *(float2*)(p3 + 2) = make_float2(r3[2], r3[3]);
        *(float2*)(p3 + 4) = make_float2(r3[4], r3[5]);
        float* p4 = P + PL4 + ab * 36;
#pragma unroll
        for (int i = 0; i < 9; ++i)
            *(float4*)(p4 + 4 * i) =
                make_float4(r4[4 * i], r4[4 * i + 1], r4[4 * i + 2], r4[4 * i + 3]);
    }
}

// ---------------- Chen pair-combine helpers (padded layout) -----------------
// Group g: 0 -> L1; 1..6 -> L2 row a; 7..42 -> L3 row ab; 43..258 -> L4 row abc.
// A,B are padded 1568-float signatures (global or LDS via generic pointer).
__device__ __forceinline__ void chen_vals(const float* __restrict__ A,
                                          const float* __restrict__ B,
                                          int g, float* v) {
    if (g == 0) {
#pragma unroll
        for (int d = 0; d < 6; ++d) v[d] = A[PL1 + d] + B[PL1 + d];
    } else if (g < 7) {
        int a = g - 1;
        float a1 = A[PL1 + a];
        const float* Ar = A + PL2 + a * 6;
        const float* Br = B + PL2 + a * 6;
#pragma unroll
        for (int d = 0; d < 6; ++d) v[d] = Ar[d] + Br[d] + a1 * B[PL1 + d];
    } else if (g < 43) {
        int ab = g - 7, a = ab / 6, b = ab - a * 6;
        float a2 = A[PL2 + ab], a1 = A[PL1 + a];
        const float* Ar = A + PL3 + ab * 6;
        const float* Br = B + PL3 + ab * 6;
        const float* B2r = B + PL2 + b * 6;
#pragma unroll
        for (int d = 0; d < 6; ++d)
            v[d] = Ar[d] + Br[d] + a2 * B[PL1 + d] + a1 * B2r[d];
    } else {
        int abc = g - 43, ab = abc / 6, cc = abc - ab * 6, a = abc / 36,
            bc = abc - a * 36;
        float a3 = A[PL3 + abc], a2 = A[PL2 + ab], a1 = A[PL1 + a];
        const float* Ar = A + PL4 + abc * 6;
        const float* Br = B + PL4 + abc * 6;
        const float* B2r = B + PL2 + cc * 6;
        const float* B3r = B + PL3 + bc * 6;
#pragma unroll
        for (int d = 0; d < 6; ++d)
            v[d] = Ar[d] + Br[d] + a3 * B[PL1 + d] + a2 * B2r[d] + a1 * B3r[d];
    }
}

__device__ __forceinline__ int grp_off_padded(int g) {
    if (g == 0) return PL1;
    if (g < 7) return PL2 + (g - 1) * 6;
    if (g < 43) return PL3 + (g - 7) * 6;
    return PL4 + (g - 43) * 6;
}
__device__ __forceinline__ int grp_off_flat(int g) {
    if (g == 0) return 0;
    if (g < 7) return 6 + (g - 1) * 6;
    if (g < 43) return 42 + (g - 7) * 6;
    return 258 + (g - 43) * 6;
}

__device__ __forceinline__ void write_final(float* out, int flat_out, int g,
                                            const float* v, int blk) {
    if (flat_out) {
        int off = grp_off_flat(g);
#pragma unroll
        for (int d = 0; d < 6; ++d) out[off + d] = v[d];
    } else {
        float* O = out + (size_t)blk * PSTRIDE;
        int off = grp_off_padded(g);
#pragma unroll
        for (int d = 0; d < 6; ++d) O[off + d] = v[d];
    }
}

// ---------------- Kernel 2: radix-gs in-block Chen tree (gs up to 32) -------
__global__ __launch_bounds__(256) void sig_tree(const float* __restrict__ in,
                                                float* __restrict__ out,
                                                int gs, int flat_out) {
    __shared__ float buf0[16 * PSTRIDE];  // 100.4 KB
    __shared__ float buf1[8 * PSTRIDE];   // 50.2 KB  (total 150.5 KB <= 160 KB)
    const int t = threadIdx.x;
    const float* gbase = in + (size_t)blockIdx.x * gs * PSTRIDE;

    int np = gs >> 1;
    // level 0: pairs read directly from global (L2-hot)
    for (int idx = t; idx < np * NGRP; idx += 256) {
        int p = idx / NGRP, g = idx - p * NGRP;
        const float* A = gbase + (size_t)(2 * p) * PSTRIDE;
        float v[6];
        chen_vals(A, A + PSTRIDE, g, v);
        if (np == 1) {
            write_final(out, flat_out, g, v, blockIdx.x);
        } else {
            float* o = buf0 + p * PSTRIDE + grp_off_padded(g);
#pragma unroll
            for (int d = 0; d < 6; ++d) o[d] = v[d];
        }
    }
    if (np == 1) return;

    float* cur = buf0;
    float* nxt = buf1;
    while (np > 1) {
        __syncthreads();
        np >>= 1;
        for (int idx = t; idx < np * NGRP; idx += 256) {
            int p = idx / NGRP, g = idx - p * NGRP;
            const float* A = cur + (2 * p) * PSTRIDE;
            float v[6];
            chen_vals(A, A + PSTRIDE, g, v);
            if (np == 1) {
                write_final(out, flat_out, g, v, blockIdx.x);
            } else {
                float* o = nxt + p * PSTRIDE + grp_off_padded(g);
#pragma unroll
                for (int d = 0; d < 6; ++d) o[d] = v[d];
            }
        }
        float* tmp = cur; cur = nxt; nxt = tmp;
    }
}

// ---------------------------------------------------------------------------
extern "C" void kernel_launch(void* const* d_in, const int* in_sizes, int n_in,
                              void* d_out, int out_size, void* d_ws, size_t ws_size,
                              hipStream_t stream) {
    const float* x = (const float*)d_in[0];
    float* out = (float*)d_out;
    float* ws0 = (float*)d_ws;                          // 1024 padded partials
    float* ws1 = ws0 + (size_t)NCHUNK * PSTRIDE;        // 32 padded partials

    sig_fold<<<NCHUNK, 64, 0, stream>>>(x, ws0);        // 65535 segs -> 1024
    sig_tree<<<32, 256, 0, stream>>>(ws0, ws1, 32, 0);  // 1024 -> 32
    sig_tree<<<1, 256, 0, stream>>>(ws1, out, 32, 1);   // 32   -> 1
}

// Round 4
// 92.025 us; speedup vs baseline: 1.4934x; 1.4934x over previous
//
#include <hip/hip_runtime.h>

#define DIM 6
#define NSEG 65535
#define CH 64             // segments per chunk (per wave)
#define WPB 4             // waves (=chunks) per fold block
#define NBLK 256          // fold blocks; NBLK*WPB*CH >= NSEG -> 256 partials

// Padded partial-signature layout (per chunk), stride in floats.
// 16B-aligned sections: L1@0(6), L2@8(36), L3@48(216), L4@264(1296)
#define PSTRIDE 1568
#define PL1 0
#define PL2 8
#define PL3 48
#define PL4 264
#define NGRP 259          // 1 + 6 + 36 + 216 output groups of 6

// ---------------- Chen pair-combine helpers (padded layout) -----------------
// Group g: 0 -> L1; 1..6 -> L2 row a; 7..42 -> L3 row ab; 43..258 -> L4 row abc.
// A,B are padded 1568-float signatures (global or LDS via generic pointer).
__device__ __forceinline__ void chen_vals(const float* __restrict__ A,
                                          const float* __restrict__ B,
                                          int g, float* v) {
    if (g == 0) {
#pragma unroll
        for (int d = 0; d < 6; ++d) v[d] = A[PL1 + d] + B[PL1 + d];
    } else if (g < 7) {
        int a = g - 1;
        float a1 = A[PL1 + a];
        const float* Ar = A + PL2 + a * 6;
        const float* Br = B + PL2 + a * 6;
#pragma unroll
        for (int d = 0; d < 6; ++d) v[d] = Ar[d] + Br[d] + a1 * B[PL1 + d];
    } else if (g < 43) {
        int ab = g - 7, a = ab / 6, b = ab - a * 6;
        float a2 = A[PL2 + ab], a1 = A[PL1 + a];
        const float* Ar = A + PL3 + ab * 6;
        const float* Br = B + PL3 + ab * 6;
        const float* B2r = B + PL2 + b * 6;
#pragma unroll
        for (int d = 0; d < 6; ++d)
            v[d] = Ar[d] + Br[d] + a2 * B[PL1 + d] + a1 * B2r[d];
    } else {
        int abc = g - 43, ab = abc / 6, cc = abc - ab * 6, a = abc / 36,
            bc = abc - a * 36;
        float a3 = A[PL3 + abc], a2 = A[PL2 + ab], a1 = A[PL1 + a];
        const float* Ar = A + PL4 + abc * 6;
        const float* Br = B + PL4 + abc * 6;
        const float* B2r = B + PL2 + cc * 6;
        const float* B3r = B + PL3 + bc * 6;
#pragma unroll
        for (int d = 0; d < 6; ++d)
            v[d] = Ar[d] + Br[d] + a3 * B[PL1 + d] + a2 * B2r[d] + a1 * B3r[d];
    }
}

__device__ __forceinline__ int grp_off_padded(int g) {
    if (g == 0) return PL1;
    if (g < 7) return PL2 + (g - 1) * 6;
    if (g < 43) return PL3 + (g - 7) * 6;
    return PL4 + (g - 43) * 6;
}
__device__ __forceinline__ int grp_off_flat(int g) {
    if (g == 0) return 0;
    if (g < 7) return 6 + (g - 1) * 6;
    if (g < 43) return 42 + (g - 7) * 6;
    return 258 + (g - 43) * 6;
}

__device__ __forceinline__ void write_final(float* out, int flat_out, int g,
                                            const float* v, int blk) {
    if (flat_out) {
        int off = grp_off_flat(g);
#pragma unroll
        for (int d = 0; d < 6; ++d) out[off + d] = v[d];
    } else {
        float* O = out + (size_t)blk * PSTRIDE;
        int off = grp_off_padded(g);
#pragma unroll
        for (int d = 0; d < 6; ++d) O[off + d] = v[d];
    }
}

// ---------------- Kernel 1: 4 waves/block, one 64-seg chunk per wave --------
// Each wave runs the proven register-resident Chen fold over CH=64 segments,
// writes its partial to LDS, then the block Chen-combines 4 partials -> 1
// (radix-4, 2 levels, proven correct in an earlier round) and writes ONE
// global partial.  256 blocks -> 256 partials (tree input 1.6 MB, not 6.4).
__global__ __launch_bounds__(256) void sig_fold4(const float* __restrict__ x,
                                                 float* __restrict__ part) {
    __shared__ __align__(16) float dxs[WPB * CH * 8];  // 8 KB
    __shared__ __align__(16) float P[WPB * PSTRIDE];   // 25.1 KB per-wave partials
    __shared__ __align__(16) float Q[2 * PSTRIDE];     // 12.5 KB combine buffer
    const int t = threadIdx.x;
    const int w = t >> 6;                 // wave id 0..3
    const int lane = t & 63;
    const int c = blockIdx.x * WPB + w;   // chunk id 0..1023
    const int j0 = c * CH;
    const int cnt = min(CH, NSEG - j0);   // 64, or 63 for the last chunk

    float* dxw = dxs + w * (CH * 8);
    for (int f = lane; f < CH * 8; f += 64) dxw[f] = 0.f;
    __syncthreads();
    const float* xb = x + (size_t)j0 * DIM;
    for (int f = lane; f < cnt * DIM; f += 64) {
        int j = f / 6, k = f - j * 6;
        dxw[j * 8 + k] = xb[f + 6] - xb[f];
    }
    __syncthreads();

    const int ab = (lane < 36) ? lane : 35;
    const int a = ab / 6, b = ab - a * 6;
    const float* dxap = dxw + a;          // lane-varying LDS bases
    const float* dxbp = dxw + b;

    float r4[36], r3[6], r2 = 0.f, s1 = 0.f;
#pragma unroll
    for (int i = 0; i < 36; ++i) r4[i] = 0.f;
#pragma unroll
    for (int i = 0; i < 6; ++i) r3[i] = 0.f;

#pragma unroll 2
    for (int j = 0; j < CH; ++j) {
        const float4 q0 = *(const float4*)(dxw + j * 8);
        const float2 q1 = *(const float2*)(dxw + j * 8 + 4);
        const float dxv[6] = {q0.x, q0.y, q0.z, q0.w, q1.x, q1.y}; // const-idx only
        const float dxa = dxap[j * 8];    // ds_read lane-addressed
        const float dxb = dxbp[j * 8];

        // t2 = S2 + dx_b*(S1/3 + dx_a/12)            (old S2, S1)
        float t2 = fmaf(dxb, fmaf(dxa, (1.f / 12.f), s1 * (1.f / 3.f)), r2);
        float t2h = 0.5f * t2;                        // *0.5 is exact
        // S4[cd] += (S3[c] + t2*0.5*dx[c]) * dx[d]   (old S3)
        float wv[6];
#pragma unroll
        for (int cc = 0; cc < 6; ++cc) wv[cc] = fmaf(t2h, dxv[cc], r3[cc]);
#pragma unroll
        for (int cc = 0; cc < 6; ++cc)
#pragma unroll
            for (int d = 0; d < 6; ++d)
                r4[cc * 6 + d] = fmaf(wv[cc], dxv[d], r4[cc * 6 + d]);
        // S3[c] += (S2 + t3*0.5*dx_b) * dx[c],  t3 = S1 + dx_a/3
        float t3 = fmaf(dxa, (1.f / 3.f), s1);
        float v = fmaf(0.5f * t3, dxb, r2);
#pragma unroll
        for (int cc = 0; cc < 6; ++cc) r3[cc] = fmaf(v, dxv[cc], r3[cc]);
        // S2 += (S1 + 0.5*dx_a) * dx_b ; S1 += dx_a
        r2 = fmaf(fmaf(0.5f, dxa, s1), dxb, r2);
        s1 += dxa;
    }

    // write wave partial into LDS (padded layout)
    if (lane < 36) {
        float* Pw = P + w * PSTRIDE;
        if (a == b) Pw[PL1 + a] = s1;
        Pw[PL2 + ab] = r2;
        float* p3 = Pw + PL3 + ab * 6;
        *(float2*)(p3 + 0) = make_float2(r3[0], r3[1]);
        *(float2*)(p3 + 2) = make_float2(r3[2], r3[3]);
        *(float2*)(p3 + 4) = make_float2(r3[4], r3[5]);
        float* p4 = Pw + PL4 + ab * 36;
#pragma unroll
        for (int i = 0; i < 9; ++i)
            *(float4*)(p4 + 4 * i) =
                make_float4(r4[4 * i], r4[4 * i + 1], r4[4 * i + 2], r4[4 * i + 3]);
    }
    __syncthreads();

    // level 1: (P0,P1)->Q0, (P2,P3)->Q1   (path order preserved)
    for (int idx = t; idx < 2 * NGRP; idx += 256) {
        int p = idx / NGRP, g = idx - p * NGRP;
        float v[6];
        chen_vals(P + (2 * p) * PSTRIDE, P + (2 * p + 1) * PSTRIDE, g, v);
        float* o = Q + p * PSTRIDE + grp_off_padded(g);
#pragma unroll
        for (int d = 0; d < 6; ++d) o[d] = v[d];
    }
    __syncthreads();

    // level 2: Q0*Q1 -> global partial for this block
    for (int idx = t; idx < NGRP; idx += 256) {
        float v[6];
        chen_vals(Q, Q + PSTRIDE, idx, v);
        float* O = part + (size_t)blockIdx.x * PSTRIDE + grp_off_padded(idx);
#pragma unroll
        for (int d = 0; d < 6; ++d) O[d] = v[d];
    }
}

// ---------------- Kernel 2: staged radix-(2*np0) in-block Chen tree ---------
// Stages gs = 2*np0 input partials into LDS with COALESCED float4 streams
// (replacing the latency-bound scattered global gather), then runs all Chen
// levels out of LDS.  np0 in {4, 2}.  LDS = 75.3 KB.
__global__ __launch_bounds__(256) void sig_tree_s(const float* __restrict__ in,
                                                  float* __restrict__ out,
                                                  int np0, int flat_out) {
    __shared__ __align__(16) float LIN[8 * PSTRIDE];  // 50.2 KB staged inputs
    __shared__ __align__(16) float W[4 * PSTRIDE];    // 25.1 KB ping-pong
    const int t = threadIdx.x;
    const int gs = np0 * 2;
    const float* gbase = in + (size_t)blockIdx.x * gs * PSTRIDE;

    // coalesced staging: gs*PSTRIDE floats as float4 streams
    const int nvec = gs * (PSTRIDE / 4);
    for (int f = t; f < nvec; f += 256)
        *(float4*)(LIN + 4 * f) = *(const float4*)(gbase + 4 * f);
    __syncthreads();

    float* cur = LIN;
    float* nxt = W;
    for (int np = np0;; np >>= 1) {
        for (int idx = t; idx < np * NGRP; idx += 256) {
            int p = idx / NGRP, g = idx - p * NGRP;
            float v[6];
            chen_vals(cur + (2 * p) * PSTRIDE, cur + (2 * p + 1) * PSTRIDE, g, v);
            if (np == 1) {
                write_final(out, flat_out, g, v, blockIdx.x);
            } else {
                float* o = nxt + p * PSTRIDE + grp_off_padded(g);
#pragma unroll
                for (int d = 0; d < 6; ++d) o[d] = v[d];
            }
        }
        if (np == 1) break;
        __syncthreads();
        float* tmp = cur; cur = nxt; nxt = tmp;
    }
}

// ---------------------------------------------------------------------------
extern "C" void kernel_launch(void* const* d_in, const int* in_sizes, int n_in,
                              void* d_out, int out_size, void* d_ws, size_t ws_size,
                              hipStream_t stream) {
    const float* x = (const float*)d_in[0];
    float* out = (float*)d_out;
    float* ws0 = (float*)d_ws;                          // 256 padded partials
    float* ws1 = ws0 + (size_t)NBLK * PSTRIDE;          // 32 padded partials
    float* ws2 = ws1 + (size_t)32 * PSTRIDE;            // 4 padded partials

    sig_fold4<<<NBLK, 256, 0, stream>>>(x, ws0);        // 65535 segs -> 256
    sig_tree_s<<<32, 256, 0, stream>>>(ws0, ws1, 4, 0); // 256 -> 32
    sig_tree_s<<<4, 256, 0, stream>>>(ws1, ws2, 4, 0);  // 32  -> 4
    sig_tree_s<<<1, 256, 0, stream>>>(ws2, out, 2, 1);  // 4   -> 1
}